// Round 4
// baseline (258.366 us; speedup 1.0000x reference)
//
#include <hip/hip_runtime.h>
#include <math.h>

// Strict IEEE fp32, no FMA contraction anywhere: we must replicate the CPU
// LAPACK (OpenBLAS reference, generic x86-64 = no FMA) rounding sequence in
// the eigensolver so that per-bin eigenvector SIGNS match bit-for-bit paths.
#pragma clang fp contract(off)

typedef float2 cplx;

__device__ __forceinline__ cplx cmk(float x, float y){ cplx r; r.x=x; r.y=y; return r; }
__device__ __forceinline__ cplx cadd(cplx a, cplx b){ return cmk(a.x+b.x, a.y+b.y); }
__device__ __forceinline__ cplx csub(cplx a, cplx b){ return cmk(a.x-b.x, a.y-b.y); }
__device__ __forceinline__ cplx cmul(cplx a, cplx b){ return cmk(a.x*b.x - a.y*b.y, a.x*b.y + a.y*b.x); }
__device__ __forceinline__ cplx conjc(cplx a){ return cmk(a.x, -a.y); }

__device__ __forceinline__ float fsign(float a, float b){
    float aa = fabsf(a);
    return (b >= 0.f) ? aa : -aa;
}

// SLAPY2: W*SQRT(1+(Z/W)^2)
__device__ __forceinline__ float lapy2(float x, float y){
    float xa = fabsf(x), ya = fabsf(y);
    float w = fmaxf(xa, ya), z = fminf(xa, ya);
    if (z == 0.f) return w;
    float q = z / w;
    return w * sqrtf(1.f + q*q);
}

// SLAPY3
__device__ __forceinline__ float lapy3(float x, float y, float z){
    float xa = fabsf(x), ya = fabsf(y), za = fabsf(z);
    float w = fmaxf(fmaxf(xa, ya), za);
    if (w == 0.f) return xa + ya + za;
    float a = xa/w, b = ya/w, c = za/w;
    return w * sqrtf(a*a + b*b + c*c);
}

// SLADIV2 (LAPACK >= 3.5, Baudin-Smith)
__device__ __forceinline__ float sladiv2(float a, float b, float c, float d,
                                         float r, float t){
    if (r != 0.f) {
        float br = b*r;
        if (br != 0.f) return (a + br)*t;
        return a*t + (b*t)*r;
    }
    return (a + d*(b/c))*t;
}

// SLADIV1
__device__ __forceinline__ void sladiv1(float a, float b, float c, float d,
                                        float* p, float* q){
    float r = d / c;
    float t = 1.f / (c + d*r);
    *p = sladiv2(a, b, c, d, r, t);
    a = -a;
    *q = sladiv2(b, a, c, d, r, t);
}

// CLADIV via SLADIV (no scaling branch: our magnitudes are O(1e-3..1e2))
__device__ __forceinline__ cplx ladiv(cplx x, cplx y){
    float p, q;
    if (fabsf(y.y) <= fabsf(y.x)) {
        sladiv1(x.x, x.y, y.x, y.y, &p, &q);
    } else {
        sladiv1(x.y, x.x, y.y, y.x, &p, &q);
        q = -q;
    }
    return cmk(p, q);
}

// SLARTG, LAPACK >= 3.10 convention
__device__ __forceinline__ void lartg(float f, float g, float* cs, float* sn, float* r)
{
    const float SAFMIN = 1.1754944e-38f;
    const float SAFMAX = 8.5070592e+37f;
    const float RTMIN  = 1.0842022e-19f;
    const float RTMAX  = 6.5249474e+18f;
    if (g == 0.f) { *cs = 1.f; *sn = 0.f; *r = f; }
    else if (f == 0.f) { *cs = 0.f; *sn = (g > 0.f) ? 1.f : -1.f; *r = fabsf(g); }
    else {
        float f1 = fabsf(f), g1 = fabsf(g);
        if (f1 > RTMIN && f1 < RTMAX && g1 > RTMIN && g1 < RTMAX) {
            float d = sqrtf(f*f + g*g);
            *cs = f1 / d;
            *r = (f >= 0.f) ? d : -d;
            *sn = g / *r;
        } else {
            float uu = fminf(SAFMAX, fmaxf(SAFMIN, fmaxf(f1, g1)));
            float fs = f/uu, gs = g/uu;
            float d = sqrtf(fs*fs + gs*gs);
            *cs = fabsf(fs)/d;
            *r = ((f >= 0.f) ? d : -d)*uu;
            *sn = g / *r;
        }
    }
}

// SLAEV2 (verbatim)
__device__ __forceinline__ void laev2(float a, float b, float c,
                                      float* rt1, float* rt2, float* cs1, float* sn1)
{
    float sm = a + c, df = a - c, adf = fabsf(df), tb = b + b, ab = fabsf(tb);
    float acmx, acmn;
    if (fabsf(a) > fabsf(c)) { acmx = a; acmn = c; } else { acmx = c; acmn = a; }
    float rt;
    if (adf > ab)      { float q = ab/adf; rt = adf*sqrtf(1.f + q*q); }
    else if (adf < ab) { float q = adf/ab; rt = ab*sqrtf(1.f + q*q); }
    else               { rt = ab*sqrtf(2.f); }
    int sgn1;
    if (sm < 0.f)      { *rt1 = 0.5f*(sm - rt); sgn1 = -1; *rt2 = (acmx / *rt1)*acmn - (b / *rt1)*b; }
    else if (sm > 0.f) { *rt1 = 0.5f*(sm + rt); sgn1 =  1; *rt2 = (acmx / *rt1)*acmn - (b / *rt1)*b; }
    else               { *rt1 = 0.5f*rt; *rt2 = -0.5f*rt; sgn1 = 1; }
    float cs; int sgn2;
    if (df >= 0.f) { cs = df + rt; sgn2 = 1; } else { cs = df - rt; sgn2 = -1; }
    float acs = fabsf(cs);
    if (acs > ab) {
        float ct = -tb/cs;
        *sn1 = 1.f/sqrtf(1.f + ct*ct);
        *cs1 = ct * (*sn1);
    } else {
        if (ab == 0.f) { *cs1 = 1.f; *sn1 = 0.f; }
        else {
            float tn = -cs/tb;
            *cs1 = 1.f/sqrtf(1.f + tn*tn);
            *sn1 = tn * (*cs1);
        }
    }
    if (sgn1 == sgn2) { float tn = *cs1; *cs1 = -(*sn1); *sn1 = tn; }
}

#define NB 64

__global__ __launch_bounds__(NB) void mvdr_weights(
    const float* __restrict__ ts_re, const float* __restrict__ ts_im,
    const float* __restrict__ ns_re, const float* __restrict__ ns_im,
    float* __restrict__ wout)
{
#pragma clang fp contract(off)
    const int tid = threadIdx.x;
    const int gid = blockIdx.x*NB + tid;    // = b*512 + f
    const int b = gid >> 9;
    const int freq = gid & 511;

    __shared__ cplx  As[64*NB];   // 32 KB
    __shared__ float Zs[64*NB];   // 16 KB
    __shared__ cplx  Tau[7*NB];
    __shared__ float Dd[8*NB];
    __shared__ float Ee[7*NB];
    __shared__ float Cw[7*NB];
    __shared__ float Sw[7*NB];

#define AS(r,c)  As[((r)*8+(c))*NB + tid]
#define ZS(r,c)  Zs[(((r)-1)*8+((c)-1))*NB + tid]
#define TAUV(i)  Tau[(i)*NB + tid]
#define D1(i)    Dd[((i)-1)*NB + tid]
#define E1(i)    Ee[((i)-1)*NB + tid]
#define CW(i)    Cw[((i)-1)*NB + tid]
#define SW(i)    Sw[((i)-1)*NB + tid]

    const size_t tbase = (size_t)b*64*512 + freq;

    // ---- load target SCM LOWER TRIANGLE ONLY (cheevd 'L' semantics; NO
    // symmetrization — numpy reads A[i][j], i>=j, diag imag ignored) ----
    {
        #pragma unroll
        for (int r = 0; r < 8; r++)
            #pragma unroll
            for (int c2 = 0; c2 <= r; c2++) {
                float re = ts_re[tbase + (size_t)(r*8+c2)*512];
                float im = (r==c2) ? 0.f : ts_im[tbase + (size_t)(r*8+c2)*512];
                AS(r,c2) = cmk(re, im);
            }
    }

    // ---- chetd2 (lower), reference BLAS loop orders ----
    #pragma unroll 1
    for (int i = 0; i < 7; i++) {
        cplx alpha = AS(i+1, i);
        // SCNRM2 (3.10+ medium path): serial re^2, im^2 adds
        float xn2 = 0.f;
        for (int k = i+2; k < 8; k++) { cplx v = AS(k,i); xn2 = xn2 + v.x*v.x; xn2 = xn2 + v.y*v.y; }
        float xnorm = sqrtf(xn2);
        cplx taui; float ei;
        if (xnorm == 0.f && alpha.y == 0.f) {
            taui = cmk(0.f, 0.f); ei = alpha.x;
        } else {
            float mag = lapy3(alpha.x, alpha.y, xnorm);
            float beta = (alpha.x >= 0.f) ? -mag : mag;
            taui = cmk((beta - alpha.x)/beta, -alpha.y/beta);
            cplx inv = ladiv(cmk(1.f,0.f), cmk(alpha.x - beta, alpha.y));
            for (int k = i+2; k < 8; k++) AS(k,i) = cmul(inv, AS(k,i));   // CSCAL
            ei = beta;
        }
        if (taui.x != 0.f || taui.y != 0.f) {
            // CHEMV 'L' (reference column order), w := taui * A22 * v, beta=0
            cplx w8[8];
            for (int r = i+1; r < 8; r++) w8[r] = cmk(0.f, 0.f);
            for (int j = i+1; j < 8; j++) {
                cplx xj = (j == i+1) ? cmk(1.f,0.f) : AS(j,i);
                cplx temp1 = cmul(taui, xj);
                cplx temp2 = cmk(0.f, 0.f);
                float dj = AS(j,j).x;
                w8[j].x = w8[j].x + temp1.x*dj;
                w8[j].y = w8[j].y + temp1.y*dj;
                for (int r = j+1; r < 8; r++) {
                    cplx arj = AS(r,j);
                    cplx xr  = AS(r,i);               // r >= i+2 always here
                    w8[r] = cadd(w8[r], cmul(temp1, arj));
                    temp2 = cadd(temp2, cmul(conjc(arj), xr));
                }
                w8[j] = cadd(w8[j], cmul(taui, temp2));
            }
            // alpha2 = (-0.5*taui) * CDOTC(w, v)
            cplx dot = cmk(0.f,0.f);
            for (int r = i+1; r < 8; r++) {
                cplx v = (r == i+1) ? cmk(1.f,0.f) : AS(r,i);
                dot = cadd(dot, cmul(conjc(w8[r]), v));
            }
            cplx a2 = cmul(cmk(-0.5f*taui.x, -0.5f*taui.y), dot);
            // CAXPY: w += a2 * v
            for (int r = i+1; r < 8; r++) {
                cplx v = (r == i+1) ? cmk(1.f,0.f) : AS(r,i);
                w8[r] = cadd(w8[r], cmul(a2, v));
            }
            // CHER2 'L', alpha = -1 (reference column order)
            for (int j = i+1; j < 8; j++) {
                cplx xj = (j == i+1) ? cmk(1.f,0.f) : AS(j,i);
                cplx yj = w8[j];
                cplx temp1 = cmk(-yj.x, yj.y);        // (-1)*conj(y_j)
                cplx temp2 = cmk(-xj.x, xj.y);        // conj((-1)*x_j)
                // diag: REAL(A) + REAL(x*t1 + y*t2)
                cplx p1 = cmul(xj, temp1);
                cplx p2 = cmul(yj, temp2);
                AS(j,j) = cmk(AS(j,j).x + (p1.x + p2.x), 0.f);
                for (int r = j+1; r < 8; r++) {
                    cplx xr = AS(r,i);
                    cplx yr = w8[r];
                    cplx a = AS(r,j);
                    a = cadd(a, cmul(xr, temp1));
                    a = cadd(a, cmul(yr, temp2));
                    AS(r,j) = a;
                }
            }
        } else {
            AS(i+1,i+1).y = 0.f;
        }
        D1(i+1) = AS(i,i).x;
        E1(i+1) = ei;
        TAUV(i) = taui;
    }
    D1(8) = AS(7,7).x;

    // ---- ssteqr clone (csteqr compz='I'; Z real) ----
    #pragma unroll
    for (int r = 1; r <= 8; r++)
        #pragma unroll
        for (int c2 = 1; c2 <= 8; c2++)
            ZS(r,c2) = (r==c2) ? 1.f : 0.f;

    {
        const float EPS   = 5.9604645e-08f;
        const float EPS2  = 3.5527137e-15f;
        const float SAFMIN= 1.1754944e-38f;
        int l1 = 1, l = 0, lsv = 0, lend = 0, lendsv = 0, mm = 0, jtot = 0;
        float p, g, r_, c_, s_, f_, b_, rt1, rt2;

      L10:
        if (l1 > 8) goto Lsort;
        if (l1 > 1) E1(l1-1) = 0.f;
        mm = 8;
        if (l1 <= 7) {
            for (int m2 = l1; m2 <= 7; m2++) {
                float tst = fabsf(E1(m2));
                if (tst == 0.f) { mm = m2; goto L30; }
                if (tst <= (sqrtf(fabsf(D1(m2)))*sqrtf(fabsf(D1(m2+1))))*EPS) {
                    E1(m2) = 0.f; mm = m2; goto L30;
                }
            }
            mm = 8;
        }
      L30:
        l = l1; lsv = l; lend = mm; lendsv = lend; l1 = mm + 1;
        if (lend == l) goto L10;
        {
            float an = 0.f;
            for (int ii = l; ii <= lend; ii++) an = fmaxf(an, fabsf(D1(ii)));
            for (int ii = l; ii <  lend; ii++) an = fmaxf(an, fabsf(E1(ii)));
            if (an == 0.f) goto L10;
        }
        if (fabsf(D1(lend)) < fabsf(D1(l))) { lend = lsv; l = lendsv; }

        if (lend > l) {
          L40:
            if (l != lend) {
                for (mm = l; mm <= lend-1; mm++) {
                    float tst = E1(mm)*E1(mm);
                    if (tst <= (EPS2*fabsf(D1(mm)))*fabsf(D1(mm+1)) + SAFMIN) goto L60;
                }
                mm = lend;
            } else mm = lend;
          L60:
            if (mm < lend) E1(mm) = 0.f;
            p = D1(l);
            if (mm == l) goto L80;
            if (mm == l+1) {
                laev2(D1(l), E1(l), D1(l+1), &rt1, &rt2, &c_, &s_);
                for (int k = 1; k <= 8; k++) {
                    float t = ZS(k, l+1);
                    ZS(k, l+1) = c_*t - s_*ZS(k, l);
                    ZS(k, l)   = s_*t + c_*ZS(k, l);
                }
                D1(l) = rt1; D1(l+1) = rt2; E1(l) = 0.f;
                l += 2;
                if (l <= lend) goto L40;
                goto L140;
            }
            if (jtot == 240) goto L140;
            jtot++;
            g = (D1(l+1) - p) / (2.f*E1(l));
            r_ = lapy2(g, 1.f);
            g = D1(mm) - p + E1(l)/(g + fsign(r_, g));
            s_ = 1.f; c_ = 1.f; p = 0.f;
            for (int i2 = mm-1; i2 >= l; i2--) {
                f_ = s_*E1(i2); b_ = c_*E1(i2);
                lartg(g, f_, &c_, &s_, &r_);
                if (i2 != mm-1) E1(i2+1) = r_;
                g = D1(i2+1) - p;
                r_ = (D1(i2) - g)*s_ + 2.f*c_*b_;
                p = s_*r_;
                D1(i2+1) = g + p;
                g = c_*r_ - b_;
                CW(i2) = c_; SW(i2) = -s_;
            }
            for (int j2 = mm-1; j2 >= l; j2--) {      // slasr 'R','V','B'
                float cj = CW(j2), sj = SW(j2);
                for (int k = 1; k <= 8; k++) {
                    float t = ZS(k, j2+1);
                    ZS(k, j2+1) = cj*t - sj*ZS(k, j2);
                    ZS(k, j2)   = sj*t + cj*ZS(k, j2);
                }
            }
            D1(l) = D1(l) - p;
            E1(l) = g;
            goto L40;
          L80:
            D1(l) = p;
            l++;
            if (l <= lend) goto L40;
            goto L140;
        } else {
          L90:
            if (l != lend) {
                for (mm = l; mm >= lend+1; mm--) {
                    float tst = E1(mm-1)*E1(mm-1);
                    if (tst <= (EPS2*fabsf(D1(mm)))*fabsf(D1(mm-1)) + SAFMIN) goto L110;
                }
                mm = lend;
            } else mm = lend;
          L110:
            if (mm > lend) E1(mm-1) = 0.f;
            p = D1(l);
            if (mm == l) goto L130;
            if (mm == l-1) {
                laev2(D1(l-1), E1(l-1), D1(l), &rt1, &rt2, &c_, &s_);
                for (int k = 1; k <= 8; k++) {        // slasr 'R','V','F'
                    float t = ZS(k, l);
                    ZS(k, l)   = c_*t - s_*ZS(k, l-1);
                    ZS(k, l-1) = s_*t + c_*ZS(k, l-1);
                }
                D1(l-1) = rt1; D1(l) = rt2; E1(l-1) = 0.f;
                l -= 2;
                if (l >= lend) goto L90;
                goto L140;
            }
            if (jtot == 240) goto L140;
            jtot++;
            g = (D1(l-1) - p)/(2.f*E1(l-1));
            r_ = lapy2(g, 1.f);
            g = D1(mm) - p + E1(l-1)/(g + fsign(r_, g));
            s_ = 1.f; c_ = 1.f; p = 0.f;
            for (int i2 = mm; i2 <= l-1; i2++) {
                f_ = s_*E1(i2); b_ = c_*E1(i2);
                lartg(g, f_, &c_, &s_, &r_);
                if (i2 != mm) E1(i2-1) = r_;
                g = D1(i2) - p;
                r_ = (D1(i2+1) - g)*s_ + 2.f*c_*b_;
                p = s_*r_;
                D1(i2) = g + p;
                g = c_*r_ - b_;
                CW(i2) = c_; SW(i2) = s_;
            }
            for (int j2 = mm; j2 <= l-1; j2++) {      // slasr 'R','V','F'
                float cj = CW(j2), sj = SW(j2);
                for (int k = 1; k <= 8; k++) {
                    float t = ZS(k, j2+1);
                    ZS(k, j2+1) = cj*t - sj*ZS(k, j2);
                    ZS(k, j2)   = sj*t + cj*ZS(k, j2);
                }
            }
            D1(l) = D1(l) - p;
            E1(l-1) = g;
            goto L90;
          L130:
            D1(l) = p;
            l--;
            if (l >= lend) goto L90;
            goto L140;
        }
      L140:
        if (jtot < 240) goto L10;
      Lsort:
        for (int ii = 2; ii <= 8; ii++) {
            int i2 = ii-1, k2 = i2;
            p = D1(i2);
            for (int j2 = ii; j2 <= 8; j2++) if (D1(j2) < p) { k2 = j2; p = D1(j2); }
            if (k2 != i2) {
                D1(k2) = D1(i2); D1(i2) = p;
                for (int r = 1; r <= 8; r++) { float t = ZS(r,i2); ZS(r,i2) = ZS(r,k2); ZS(r,k2) = t; }
            }
        }
    }

    // ---- back-transform: atf = H(1)...H(7) * Z[:,8]  (cunm2r order) ----
    cplx u[8];
    #pragma unroll
    for (int r = 0; r < 8; r++) u[r] = cmk(ZS(r+1, 8), 0.f);
    #pragma unroll 1
    for (int i = 6; i >= 0; i--) {
        cplx taui = TAUV(i);
        if (taui.x != 0.f || taui.y != 0.f) {
            cplx dot = u[i+1];                     // v[i+1] = 1
            for (int k = i+2; k < 8; k++) dot = cadd(dot, cmul(conjc(AS(k,i)), u[k]));
            cplx td = cmul(taui, dot);
            u[i+1] = csub(u[i+1], td);
            for (int k = i+2; k < 8; k++) u[k] = csub(u[k], cmul(AS(k,i), td));
        }
    }

    // ---- noise SCM (lower, unsymmetrized), Cholesky solve ----
    {
        #pragma unroll
        for (int r = 0; r < 8; r++)
            #pragma unroll
            for (int c2 = 0; c2 <= r; c2++) {
                float re = ns_re[tbase + (size_t)(r*8+c2)*512];
                float im = (r==c2) ? 0.f : ns_im[tbase + (size_t)(r*8+c2)*512];
                AS(r,c2) = cmk(re, im);
            }
    }
    #pragma unroll 1
    for (int j = 0; j < 8; j++) {
        float sum = AS(j,j).x;
        for (int k = 0; k < j; k++) { cplx lv = AS(j,k); sum -= lv.x*lv.x + lv.y*lv.y; }
        float ljj = sqrtf(fmaxf(sum, 1e-30f));
        AS(j,j) = cmk(ljj, 0.f);
        for (int r = j+1; r < 8; r++) {
            cplx acc = AS(r,j);
            for (int k = 0; k < j; k++) acc = csub(acc, cmul(AS(r,k), conjc(AS(j,k))));
            AS(r,j) = cmk(acc.x/ljj, acc.y/ljj);
        }
    }
    cplx yv[8];
    #pragma unroll 1
    for (int r = 0; r < 8; r++) {
        cplx acc = u[r];
        for (int k = 0; k < r; k++) acc = csub(acc, cmul(AS(r,k), yv[k]));
        float inv = 1.f/AS(r,r).x;
        yv[r] = cmk(acc.x*inv, acc.y*inv);
    }
    cplx zv[8];
    #pragma unroll 1
    for (int r = 7; r >= 0; r--) {
        cplx acc = yv[r];
        for (int k = r+1; k < 8; k++) acc = csub(acc, cmul(conjc(AS(k,r)), zv[k]));
        float inv = 1.f/AS(r,r).x;
        zv[r] = cmk(acc.x*inv, acc.y*inv);
    }
    cplx den = cmk(0.f, 0.f);
    #pragma unroll
    for (int m3 = 0; m3 < 8; m3++) den = cadd(den, cmul(conjc(u[m3]), zv[m3]));
    float dn = den.x*den.x + den.y*den.y;
    float* wp = wout + (size_t)gid*16;
    #pragma unroll
    for (int m3 = 0; m3 < 8; m3++) {
        float bfr = (zv[m3].x*den.x + zv[m3].y*den.y)/dn;
        float bfi = (zv[m3].y*den.x - zv[m3].x*den.y)/dn;
        wp[2*m3]   = bfr;     // w = conj(bf)
        wp[2*m3+1] = -bfi;
    }
#undef AS
#undef ZS
#undef TAUV
#undef D1
#undef E1
#undef CW
#undef SW
}

// Output = Re(y) only (harness stores complex64 ref cast to float32).
__global__ __launch_bounds__(256) void mvdr_apply(
    const float* __restrict__ mix_re, const float* __restrict__ mix_im,
    const float* __restrict__ wbuf, float* __restrict__ out)
{
    const int bf = blockIdx.y;
    const int t = blockIdx.x*256 + threadIdx.x;
    const int b = bf >> 9, freq = bf & 511;
    if (t >= 1000) return;
    float yr = 0.f;
    #pragma unroll
    for (int m3 = 0; m3 < 8; m3++) {
        float wr = wbuf[bf*16 + 2*m3];
        float wi = wbuf[bf*16 + 2*m3 + 1];
        size_t idx = (((size_t)b*8 + m3)*512 + freq)*1000 + t;
        float xr = mix_re[idx], xi = mix_im[idx];
        yr += wr*xr - wi*xi;
    }
    out[(size_t)bf*1000 + t] = yr;
}

extern "C" void kernel_launch(void* const* d_in, const int* in_sizes, int n_in,
                              void* d_out, int out_size, void* d_ws, size_t ws_size,
                              hipStream_t stream)
{
    (void)in_sizes; (void)n_in; (void)out_size; (void)ws_size;
    const float* mix_re = (const float*)d_in[0];
    const float* mix_im = (const float*)d_in[1];
    const float* ts_re  = (const float*)d_in[2];
    const float* ts_im  = (const float*)d_in[3];
    const float* ns_re  = (const float*)d_in[4];
    const float* ns_im  = (const float*)d_in[5];
    float* wbuf = (float*)d_ws;   // 4096*16 floats = 256 KB

    mvdr_weights<<<dim3(4096/NB), dim3(NB), 0, stream>>>(ts_re, ts_im, ns_re, ns_im, wbuf);
    mvdr_apply<<<dim3(4, 4096), dim3(256), 0, stream>>>(mix_re, mix_im, wbuf, (float*)d_out);
}